// Round 1
// 101.775 us; speedup vs baseline: 1.0175x; 1.0175x over previous
//
#include <hip/hip_runtime.h>
#include <stdint.h>

// S=512, B=64, H=8, K=12, P=9, L=137, T=4096, THRESH=4
// Workspace layout (u32 units):
//   [0, 65536)       packed ram tables: 128 u32 per hb (hb-major)   = 256 KB
//   [65536, 66560)   packed token rows: 512 u64                     = 4 KB
//   [66560, 74752)   parity bits: [hb][chunk(8)][2] u32             = 32 KB
#define WS_TABLE  0
#define WS_TOKROW 65536
#define WS_PAR    66560

// ---- Kernel 0: pack ram bits and token rows once into workspace ----
__global__ __launch_bounds__(256) void softram_pack_kernel(
    const int* __restrict__ tokens,   // (512, 64)
    const float* __restrict__ ram,    // (8, 64, 4096) values in {0,1}
    uint32_t* __restrict__ ws)
{
    const int tid = threadIdx.x, lane = tid & 63, w = tid >> 6;
    if (blockIdx.x < 512) {
        const int hb = blockIdx.x;
        const float* ramp = ram + (size_t)hb * 4096;
        uint32_t* tp = ws + WS_TABLE + hb * 128;
        #pragma unroll
        for (int c = 0; c < 16; ++c) {
            float v = ramp[c * 256 + tid];
            unsigned long long m = __ballot(v > 0.5f);
            if (lane == 0) {
                tp[c * 8 + w * 2]     = (uint32_t)m;
                tp[c * 8 + w * 2 + 1] = (uint32_t)(m >> 32);
            }
        }
    } else {
        const int r = blockIdx.x - 512;          // 0..7, 16 row-groups each
        unsigned long long* tokp = (unsigned long long*)(ws + WS_TOKROW);
        for (int c = r * 16; c < r * 16 + 16; ++c) {
            int v = tokens[c * 256 + tid];       // s = c*4 + w, bit = lane (=b)
            unsigned long long m = __ballot(v != 0);
            if (lane == 0) tokp[c * 4 + w] = m;
        }
    }
}

// ---- Kernel 1: parity. 4 blocks per hb; block q owns chunks {q, 7-q};
//      each chunk is split across 2 waves by interleaved j-sub-blocks.
//      Fast path: ~44% of hb's have zero r-type connections (conn >= 128);
//      for those Ar[d] == 0 for all d, so the per-lookup ds_read_u16 ArL[d]
//      and the d/add arithmetic are dropped (wave-uniform branch). ----
__global__ __launch_bounds__(256) void softram_parity_kernel(
    const int* __restrict__ conn,     // (8, 64, 12)
    uint32_t* __restrict__ ws)
{
    __shared__ uint32_t table[128];
    __shared__ unsigned long long tokrow[512];
    __shared__ unsigned short AqL[512], AkL[512], ArL[512];
    __shared__ unsigned long long parbuf[4];

    const int tid  = threadIdx.x;
    const int lane = tid & 63;
    const int w    = tid >> 6;
    const int hb   = blockIdx.x >> 2;
    const int q    = blockIdx.x & 3;

    // stage packed table + token rows from workspace
    if (tid < 128) table[tid] = ws[WS_TABLE + hb * 128 + tid];
    {
        const unsigned long long* tokp = (const unsigned long long*)(ws + WS_TOKROW);
        tokrow[tid]       = tokp[tid];
        tokrow[tid + 256] = tokp[tid + 256];
    }
    __syncthreads();

    // per-position partial addresses (bits of addr are disjoint across q/k/r)
    const int* cp = conn + hb * 12;
    int ck[12];
    #pragma unroll
    for (int k = 0; k < 12; ++k) ck[k] = cp[k];
    bool has_r = false;
    #pragma unroll
    for (int k = 0; k < 12; ++k) has_r = has_r || (ck[k] >= 128);

    #pragma unroll
    for (int rep = 0; rep < 2; ++rep) {
        int s = tid + rep * 256;
        unsigned long long row = tokrow[s];
        int aq = 0, ak = 0, ar = 0;
        #pragma unroll
        for (int k = 0; k < 12; ++k) {
            int c = ck[k];                        // wave-uniform -> scalar branch
            if (c < 64)       aq |= (int)((row >> c) & 1ull) << k;
            else if (c < 128) ak |= (int)((row >> (c - 64)) & 1ull) << k;
            else              ar |= ((s >> (c - 128)) & 1) << k;
        }
        AqL[s] = (unsigned short)aq;
        AkL[s] = (unsigned short)ak;
        ArL[s] = (unsigned short)ar;
    }
    __syncthreads();

    // waves 0,1 -> chunk q (halves 0,1); waves 2,3 -> chunk 7-q (halves 0,1)
    const int c  = (w < 2) ? q : (7 - q);
    const int hh = w & 1;
    const int i  = c * 64 + lane;                // this lane's output row
    const int aq = (int)AqL[i];
    uint32_t acc = 0;

    if (!has_r) {
        // ---- fast path: addr = aq + ak only (Ar == 0 everywhere) ----
        for (int sb = hh; sb < c; sb += 2) {
            int akv = (int)AkL[sb * 64 + lane];
            #pragma unroll
            for (int jj = 0; jj < 64; ++jj) {
                int addr = aq + __builtin_amdgcn_readlane(akv, jj);
                acc ^= table[addr >> 5] >> (addr & 31);
            }
        }
        if (hh == (c & 1)) {
            int akv = (int)AkL[c * 64 + lane];
            #pragma unroll
            for (int jj = 0; jj < 64; ++jj) {
                int addr = aq + __builtin_amdgcn_readlane(akv, jj);
                uint32_t bit = table[addr >> 5] >> (addr & 31);
                acc ^= (lane >= jj) ? bit : 0u;
            }
        }
    } else {
        // ---- general path ----
        // full sub-blocks sb in [0, c), this wave takes sb ≡ hh (mod 2)
        for (int sb = hh; sb < c; sb += 2) {
            int akv = (int)AkL[sb * 64 + lane];
            #pragma unroll
            for (int jj = 0; jj < 64; ++jj) {
                int sak = __builtin_amdgcn_readlane(akv, jj);   // wave-uniform Ak[j]
                int d = i - sb * 64 - jj;                       // >= 1 here
                int addr = aq + sak + (int)ArL[d];
                acc ^= table[addr >> 5] >> (addr & 31);         // parity in bit 0
            }
        }
        // tail sub-block sb == c (j <= i masking), owned by the matching-parity wave
        if (hh == (c & 1)) {
            int akv = (int)AkL[c * 64 + lane];
            #pragma unroll
            for (int jj = 0; jj < 64; ++jj) {
                int sak = __builtin_amdgcn_readlane(akv, jj);
                int d = lane - jj;
                int dm = d < 0 ? 0 : d;
                int addr = aq + sak + (int)ArL[dm];
                uint32_t bit = table[addr >> 5] >> (addr & 31);
                acc ^= (d >= 0) ? bit : 0u;
            }
        }
    }
    acc &= 1u;
    unsigned long long m = __ballot(acc != 0);
    if (lane == 0) parbuf[w] = m;
    __syncthreads();

    if (tid == 0) {
        unsigned long long m0 = parbuf[0] ^ parbuf[1];      // chunk q
        unsigned long long m1 = parbuf[2] ^ parbuf[3];      // chunk 7-q
        uint32_t* wp = ws + WS_PAR;
        wp[(hb * 8 + q) * 2]           = (uint32_t)m0;
        wp[(hb * 8 + q) * 2 + 1]       = (uint32_t)(m0 >> 32);
        wp[(hb * 8 + (7 - q)) * 2]     = (uint32_t)m1;
        wp[(hb * 8 + (7 - q)) * 2 + 1] = (uint32_t)(m1 >> 32);
    }
}

// ---- Kernel 2: majority vote over heads ----
__global__ __launch_bounds__(256) void softram_vote_kernel(
    const uint32_t* __restrict__ ws, float* __restrict__ out)
{
    int t = blockIdx.x * 256 + threadIdx.x;      // t = i*64 + b, 32768 total
    int b = t & 63;
    int i = t >> 6;
    const uint32_t* wp = ws + WS_PAR;
    int sum = 0;
    #pragma unroll
    for (int h = 0; h < 8; ++h) {
        int hb = h * 64 + b;
        uint32_t wv = wp[(hb * 8 + (i >> 6)) * 2 + ((i >> 5) & 1)];
        sum += (wv >> (i & 31)) & 1u;
    }
    out[t] = (sum > 4) ? 1.0f : 0.0f;            // THRESH = H/2 = 4
}

extern "C" void kernel_launch(void* const* d_in, const int* in_sizes, int n_in,
                              void* d_out, int out_size, void* d_ws, size_t ws_size,
                              hipStream_t stream) {
    const int*   tokens = (const int*)d_in[0];   // (512, 64)
    const int*   conn   = (const int*)d_in[1];   // (8, 64, 12)
    const float* ram    = (const float*)d_in[2]; // (8, 64, 4096)
    float*       out    = (float*)d_out;         // (512, 64)
    uint32_t*    ws     = (uint32_t*)d_ws;       // needs ~300 KB

    softram_pack_kernel<<<520, 256, 0, stream>>>(tokens, ram, ws);
    softram_parity_kernel<<<2048, 256, 0, stream>>>(conn, ws);
    softram_vote_kernel<<<128, 256, 0, stream>>>(ws, out);
}

// Round 2
// 101.457 us; speedup vs baseline: 1.0207x; 1.0031x over previous
//
#include <hip/hip_runtime.h>
#include <stdint.h>

// S=512, B=64, H=8, K=12, P=9, L=137, T=4096, THRESH=4
// Workspace layout (u32 units):
//   [0, 65536)       packed ram tables: 128 u32 per hb (hb-major)   = 256 KB
//   [65536, 66560)   packed token rows: 512 u64                     = 4 KB
//   [66560, 74752)   parity bits: [hb][chunk(8)][2] u32             = 32 KB
#define WS_TABLE  0
#define WS_TOKROW 65536
#define WS_PAR    66560

// ---- Kernel 0: pack ram bits and token rows once into workspace ----
__global__ __launch_bounds__(256) void softram_pack_kernel(
    const int* __restrict__ tokens,   // (512, 64)
    const float* __restrict__ ram,    // (8, 64, 4096) values in {0,1}
    uint32_t* __restrict__ ws)
{
    const int tid = threadIdx.x, lane = tid & 63, w = tid >> 6;
    if (blockIdx.x < 512) {
        const int hb = blockIdx.x;
        const float* ramp = ram + (size_t)hb * 4096;
        uint32_t* tp = ws + WS_TABLE + hb * 128;
        #pragma unroll
        for (int c = 0; c < 16; ++c) {
            float v = ramp[c * 256 + tid];
            unsigned long long m = __ballot(v > 0.5f);
            if (lane == 0) {
                tp[c * 8 + w * 2]     = (uint32_t)m;
                tp[c * 8 + w * 2 + 1] = (uint32_t)(m >> 32);
            }
        }
    } else {
        const int r = blockIdx.x - 512;          // 0..7, 16 row-groups each
        unsigned long long* tokp = (unsigned long long*)(ws + WS_TOKROW);
        for (int c = r * 16; c < r * 16 + 16; ++c) {
            int v = tokens[c * 256 + tid];       // s = c*4 + w, bit = lane (=b)
            unsigned long long m = __ballot(v != 0);
            if (lane == 0) tokp[c * 4 + w] = m;
        }
    }
}

// Inner parity loops, specialized by the number of r-type connections.
// NR=0: ar==0. NR=1/2: ar computed in VALU from bits of d (p*/k* are
// block-uniform -> SGPRs). NR>=3 (~4.5% of hb): fall back to the ArL LDS read.
// Rationale: the kernel is LDS-pipe-bound (per-CU resource, 32 waves share);
// moving the Ar lookup to VALU trades 2 LDS clk for ~4 VALU clk on a SIMD
// with ~2x headroom.
template<int NR>
__device__ __forceinline__ uint32_t parity_rows(
    const uint32_t* table, const unsigned short* AqL, const unsigned short* AkL,
    const unsigned short* ArL, int c, int hh, int lane,
    int p1, int k1, int p2, int k2)
{
    const int i = c * 64 + lane;                 // this lane's output row
    const int aq = (int)AqL[i];
    uint32_t acc = 0;

    // full sub-blocks sb in [0, c), this wave takes sb ≡ hh (mod 2)
    for (int sb = hh; sb < c; sb += 2) {
        int akv = (int)AkL[sb * 64 + lane];
        int dbase = i - sb * 64;                 // d >= 1 throughout
        #pragma unroll
        for (int jj = 0; jj < 64; ++jj) {
            int sak = __builtin_amdgcn_readlane(akv, jj);   // wave-uniform Ak[j]
            int d = dbase - jj;
            int ar;
            if (NR == 0)      ar = 0;
            else if (NR == 1) ar = ((d >> p1) & 1) << k1;
            else if (NR == 2) ar = (((d >> p1) & 1) << k1) | (((d >> p2) & 1) << k2);
            else              ar = (int)ArL[d];
            int addr = aq + sak + ar;
            acc ^= table[addr >> 5] >> (addr & 31);         // parity in bit 0
        }
    }
    // tail sub-block sb == c (j <= i masking), owned by the matching-parity wave
    if (hh == (c & 1)) {
        int akv = (int)AkL[c * 64 + lane];
        #pragma unroll
        for (int jj = 0; jj < 64; ++jj) {
            int sak = __builtin_amdgcn_readlane(akv, jj);
            int d = lane - jj;
            int ar;
            if (NR == 0)      ar = 0;
            else if (NR == 1) ar = ((d >> p1) & 1) << k1;       // d<0 ok: bit masked below,
            else if (NR == 2) ar = (((d >> p1) & 1) << k1)      // addr stays < 4096 (disjoint bits)
                                 | (((d >> p2) & 1) << k2);
            else { int dm = d < 0 ? 0 : d; ar = (int)ArL[dm]; }
            int addr = aq + sak + ar;
            uint32_t bit = table[addr >> 5] >> (addr & 31);
            acc ^= (d >= 0) ? bit : 0u;
        }
    }
    return acc;
}

// ---- Kernel 1: parity. 4 blocks per hb; block q owns chunks {q, 7-q};
//      each chunk is split across 2 waves by interleaved j-sub-blocks. ----
__global__ __launch_bounds__(256) void softram_parity_kernel(
    const int* __restrict__ conn,     // (8, 64, 12)
    uint32_t* __restrict__ ws)
{
    __shared__ uint32_t table[128];
    __shared__ unsigned long long tokrow[512];
    __shared__ unsigned short AqL[512], AkL[512], ArL[512];
    __shared__ unsigned long long parbuf[4];

    const int tid  = threadIdx.x;
    const int lane = tid & 63;
    const int w    = tid >> 6;
    const int hb   = blockIdx.x >> 2;
    const int q    = blockIdx.x & 3;

    // stage packed table + token rows from workspace
    if (tid < 128) table[tid] = ws[WS_TABLE + hb * 128 + tid];
    {
        const unsigned long long* tokp = (const unsigned long long*)(ws + WS_TOKROW);
        tokrow[tid]       = tokp[tid];
        tokrow[tid + 256] = tokp[tid + 256];
    }
    __syncthreads();

    // per-position partial addresses (bits of addr are disjoint across q/k/r)
    const int* cp = conn + hb * 12;
    int ck[12];
    #pragma unroll
    for (int k = 0; k < 12; ++k) ck[k] = cp[k];

    // collect r-type connections (block-uniform)
    int nr = 0, p1 = 0, k1 = 0, p2 = 0, k2 = 0;
    #pragma unroll
    for (int k = 0; k < 12; ++k) {
        if (ck[k] >= 128) {
            if (nr == 0)      { p1 = ck[k] - 128; k1 = k; }
            else if (nr == 1) { p2 = ck[k] - 128; k2 = k; }
            ++nr;
        }
    }

    #pragma unroll
    for (int rep = 0; rep < 2; ++rep) {
        int s = tid + rep * 256;
        unsigned long long row = tokrow[s];
        int aq = 0, ak = 0, ar = 0;
        #pragma unroll
        for (int k = 0; k < 12; ++k) {
            int c = ck[k];                        // wave-uniform -> scalar branch
            if (c < 64)       aq |= (int)((row >> c) & 1ull) << k;
            else if (c < 128) ak |= (int)((row >> (c - 64)) & 1ull) << k;
            else              ar |= ((s >> (c - 128)) & 1) << k;
        }
        AqL[s] = (unsigned short)aq;
        AkL[s] = (unsigned short)ak;
        ArL[s] = (unsigned short)ar;
    }
    __syncthreads();

    // waves 0,1 -> chunk q (halves 0,1); waves 2,3 -> chunk 7-q (halves 0,1)
    const int c  = (w < 2) ? q : (7 - q);
    const int hh = w & 1;

    uint32_t acc;
    if (nr == 0)      acc = parity_rows<0>(table, AqL, AkL, ArL, c, hh, lane, p1, k1, p2, k2);
    else if (nr == 1) acc = parity_rows<1>(table, AqL, AkL, ArL, c, hh, lane, p1, k1, p2, k2);
    else if (nr == 2) acc = parity_rows<2>(table, AqL, AkL, ArL, c, hh, lane, p1, k1, p2, k2);
    else              acc = parity_rows<3>(table, AqL, AkL, ArL, c, hh, lane, p1, k1, p2, k2);

    acc &= 1u;
    unsigned long long m = __ballot(acc != 0);
    if (lane == 0) parbuf[w] = m;
    __syncthreads();

    if (tid == 0) {
        unsigned long long m0 = parbuf[0] ^ parbuf[1];      // chunk q
        unsigned long long m1 = parbuf[2] ^ parbuf[3];      // chunk 7-q
        uint32_t* wp = ws + WS_PAR;
        wp[(hb * 8 + q) * 2]           = (uint32_t)m0;
        wp[(hb * 8 + q) * 2 + 1]       = (uint32_t)(m0 >> 32);
        wp[(hb * 8 + (7 - q)) * 2]     = (uint32_t)m1;
        wp[(hb * 8 + (7 - q)) * 2 + 1] = (uint32_t)(m1 >> 32);
    }
}

// ---- Kernel 2: majority vote over heads ----
__global__ __launch_bounds__(256) void softram_vote_kernel(
    const uint32_t* __restrict__ ws, float* __restrict__ out)
{
    int t = blockIdx.x * 256 + threadIdx.x;      // t = i*64 + b, 32768 total
    int b = t & 63;
    int i = t >> 6;
    const uint32_t* wp = ws + WS_PAR;
    int sum = 0;
    #pragma unroll
    for (int h = 0; h < 8; ++h) {
        int hb = h * 64 + b;
        uint32_t wv = wp[(hb * 8 + (i >> 6)) * 2 + ((i >> 5) & 1)];
        sum += (wv >> (i & 31)) & 1u;
    }
    out[t] = (sum > 4) ? 1.0f : 0.0f;            // THRESH = H/2 = 4
}

extern "C" void kernel_launch(void* const* d_in, const int* in_sizes, int n_in,
                              void* d_out, int out_size, void* d_ws, size_t ws_size,
                              hipStream_t stream) {
    const int*   tokens = (const int*)d_in[0];   // (512, 64)
    const int*   conn   = (const int*)d_in[1];   // (8, 64, 12)
    const float* ram    = (const float*)d_in[2]; // (8, 64, 4096)
    float*       out    = (float*)d_out;         // (512, 64)
    uint32_t*    ws     = (uint32_t*)d_ws;       // needs ~300 KB

    softram_pack_kernel<<<520, 256, 0, stream>>>(tokens, ram, ws);
    softram_parity_kernel<<<2048, 256, 0, stream>>>(conn, ws);
    softram_vote_kernel<<<128, 256, 0, stream>>>(ws, out);
}